// Round 11
// baseline (120.562 us; speedup 1.0000x reference)
//
#include <hip/hip_runtime.h>

// ACELoss3D round 11: 4x4x128 tile, 256 threads, 8 elems/thread (two z-packs).
// Amortizes addressing/clamp math over 8 elems and doubles loads-in-flight
// (14 float4, pinned by sched_barrier) while keeping R9/R10's L1-resident
// 4x4 footprint. y-pair exchange now __shfl_xor(.,16) (y-subs (0,1),(2,3) per
// wave); z-lines are 16 lanes, clamp lanes select-overridden.
// R7's 8-elem failure causes avoided: loads pinned (sched_barrier) + 4x4 tile
// (not 1x16 slab). History: R6 swizzle neutral; R8 sched_barrier +1.5us;
// R9 4x4 tile +3.5us; R10 y-exchange +2us.

static constexpr int   NTOT   = 6 * 128 * 128 * 128;   // 12,582,912
static constexpr int   NBLK   = 6144;                  // 32x32 xy-tiles * 6 bc
static constexpr float ALPHA_ = 0.001f;
static constexpr float MIU_   = 1.0f;
static constexpr float EPS_   = 1e-8f;

__device__ __forceinline__ void wave_reduce3(float& a, float& b, float& c) {
#pragma unroll
  for (int off = 32; off > 0; off >>= 1) {
    a += __shfl_down(a, off);
    b += __shfl_down(b, off);
    c += __shfl_down(c, off);
  }
}

// One output element. di/dj = un-halved first diffs; sx/sy = uxp+uxm, uyp+uym;
// dik/djk/dij = un-halved mixed double-diffs. 2*cik*cjk*cij = 0.25*dik*djk*dij.
__device__ __forceinline__ void elem(
    float uzm, float u0, float uzp,
    float di, float sx, float dj, float sy,
    float dik, float djk, float dij,
    float t, float& s1, float& s2, float& s3) {
  const float dk  = uzp - uzm;
  const float ci2 = 0.25f * di * di;
  const float cj2 = 0.25f * dj * dj;
  const float ck2 = 0.25f * dk * dk;
  const float u2  = u0 + u0;
  const float cii = sx - u2;
  const float cjj = sy - u2;
  const float ckk = (uzp + uzm) - u2;
  const float ss  = ci2 + cj2 + ck2;
  const float ss1 = 1.f + ss;
  const float L = (cii + cjj) + ckk;
  const float M = fmaf(ci2, cii, fmaf(cj2, cjj, ck2 * ckk));
  float curv = fmaf(ss1, L, -M);
  curv = fmaf(-0.25f * dij, dik * djk, curv);
  const float len = __builtin_amdgcn_sqrtf(EPS_ + ss);
  s3 = fmaf(curv * curv, len * __builtin_amdgcn_rcpf(ss1), s3);
  const float tm1 = t - 1.f;
  s1 = fmaf(u0, tm1 * tm1, s1);
  s2 = fmaf(1.f - u0, t * t, s2);
}

__global__ __launch_bounds__(256, 4) void ace_main(
    const float* __restrict__ pred, const float* __restrict__ truth,
    float* __restrict__ partials) {
  const int tid = threadIdx.x;
  // Block -> (bc, y-tile, x-tile); thread -> x-sub=tid>>6, y-sub=(tid>>4)&3,
  // z-group=(tid&15) (8 consecutive z each).
  const int rem = blockIdx.x & 1023;        // 32x32 xy tiles
  const int bc  = blockIdx.x >> 10;         // 0..5
  const int x   = ((rem & 31) << 2) + (tid >> 6);
  const int y   = ((rem >> 5) << 2) + ((tid >> 4) & 3);
  const int z0  = (tid & 15) << 3;                          // 0,8,...,120
  const size_t base = ((size_t)bc) << 21;
  const float* __restrict__ bp = pred + base;

  // y-pairs within the wave via bit 4: (y-sub 0,1) and (2,3).
  const bool upper = (tid & 16) != 0;
  const float sgn  = upper ? 1.f : -1.f;
  const int yOut = upper ? ((y < 127) ? y + 1 : 127) : ((y > 0) ? y - 1 : 0);
  const int rO  = yOut << 7;
  const int rC  = y << 7;
  const int pC  = x << 14;
  const int pXp = ((x < 127) ? x + 1 : 127) << 14;
  const int pXm = ((x > 0)   ? x - 1 : 0)   << 14;

  const float* rcp_ = bp + pC  + rC + z0;
  const float* rxp  = bp + pXp + rC + z0;
  const float* rxm  = bp + pXm + rC + z0;
  const float* roy  = bp + pC  + rO + z0;
  const float* rop  = bp + pXp + rO + z0;
  const float* rom  = bp + pXm + rO + z0;
  const float* rt   = truth + base + pC + rC + z0;

  // 14 float4 loads — all pinned in flight before any consumer.
  const float4 vC0 = *(const float4*)(rcp_);
  const float4 vC1 = *(const float4*)(rcp_ + 4);
  const float4 xP0 = *(const float4*)(rxp);
  const float4 xP1 = *(const float4*)(rxp + 4);
  const float4 xM0 = *(const float4*)(rxm);
  const float4 xM1 = *(const float4*)(rxm + 4);
  const float4 oY0 = *(const float4*)(roy);
  const float4 oY1 = *(const float4*)(roy + 4);
  const float4 oP0 = *(const float4*)(rop);
  const float4 oP1 = *(const float4*)(rop + 4);
  const float4 oM0 = *(const float4*)(rom);
  const float4 oM1 = *(const float4*)(rom + 4);
  const float4 t40 = *(const float4*)(rt);
  const float4 t41 = *(const float4*)(rt + 4);
#if defined(__has_builtin)
#if __has_builtin(__builtin_amdgcn_sched_barrier)
  __builtin_amdgcn_sched_barrier(0);   // keep all 14 loads issued before math
#endif
#endif

  // Center-row x combines (both packs).
  const float dxa = xP0.x - xM0.x, dxb = xP0.y - xM0.y;
  const float dxc = xP0.z - xM0.z, dxd = xP0.w - xM0.w;
  const float dxe = xP1.x - xM1.x, dxf = xP1.y - xM1.y;
  const float dxg = xP1.z - xM1.z, dxh = xP1.w - xM1.w;
  const float sxa = xP0.x + xM0.x, sxb = xP0.y + xM0.y;
  const float sxc = xP0.z + xM0.z, sxd = xP0.w + xM0.w;
  const float sxe = xP1.x + xM1.x, sxf = xP1.y + xM1.y;
  const float sxg = xP1.z + xM1.z, sxh = xP1.w + xM1.w;
  // Outward-row x-diffs.
  const float dOa = oP0.x - oM0.x, dOb = oP0.y - oM0.y;
  const float dOc = oP0.z - oM0.z, dOd = oP0.w - oM0.w;
  const float dOe = oP1.x - oM1.x, dOf = oP1.y - oM1.y;
  const float dOg = oP1.z - oM1.z, dOh = oP1.w - oM1.w;

  // Inward y-neighbor via pair exchange (partner row is never clamped).
  const float iCa = __shfl_xor(vC0.x, 16), iCb = __shfl_xor(vC0.y, 16);
  const float iCc = __shfl_xor(vC0.z, 16), iCd = __shfl_xor(vC0.w, 16);
  const float iCe = __shfl_xor(vC1.x, 16), iCf = __shfl_xor(vC1.y, 16);
  const float iCg = __shfl_xor(vC1.z, 16), iCh = __shfl_xor(vC1.w, 16);
  const float iDa = __shfl_xor(dxa, 16),   iDb = __shfl_xor(dxb, 16);
  const float iDc = __shfl_xor(dxc, 16),   iDd = __shfl_xor(dxd, 16);
  const float iDe = __shfl_xor(dxe, 16),   iDf = __shfl_xor(dxf, 16);
  const float iDg = __shfl_xor(dxg, 16),   iDh = __shfl_xor(dxh, 16);

  // y combines: sy order-free; dy/j get the half sign.
  const float sya = iCa + oY0.x, syb = iCb + oY0.y;
  const float syc = iCc + oY0.z, syd = iCd + oY0.w;
  const float sye = iCe + oY1.x, syf = iCf + oY1.y;
  const float syg = iCg + oY1.z, syh = iCh + oY1.w;
  const float dya = sgn * (oY0.x - iCa), dyb = sgn * (oY0.y - iCb);
  const float dyc = sgn * (oY0.z - iCc), dyd = sgn * (oY0.w - iCd);
  const float dye = sgn * (oY1.x - iCe), dyf = sgn * (oY1.y - iCf);
  const float dyg = sgn * (oY1.z - iCg), dyh = sgn * (oY1.w - iCh);
  const float ja  = sgn * (dOa - iDa),   jb  = sgn * (dOb - iDb);
  const float jc  = sgn * (dOc - iDc),   jd  = sgn * (dOd - iDd);
  const float je  = sgn * (dOe - iDe),   jf  = sgn * (dOf - iDf);
  const float jg  = sgn * (dOg - iDg),   jh  = sgn * (dOh - iDh);

  // z-halo from adjacent lanes (lane i-1 holds z0-8..z0-1). z-lines are 16
  // lanes; clamp lanes (tid&15)==0 / ==15 select-overridden, so +-1 shuffles
  // never leak across a z-line boundary (where y changes).
  const bool zlo = (z0 == 0), zhi = (z0 == 120);
  float clo  = __shfl_up  (vC1.w, 1);  clo  = zlo ? vC0.x : clo;
  float chi  = __shfl_down(vC0.x, 1);  chi  = zhi ? vC1.w : chi;
  float dxm1 = __shfl_up  (dxh, 1);    dxm1 = zlo ? dxa : dxm1;
  float dxp8 = __shfl_down(dxa, 1);    dxp8 = zhi ? dxh : dxp8;
  float dym1 = __shfl_up  (dyh, 1);    dym1 = zlo ? dya : dym1;
  float dyp8 = __shfl_down(dya, 1);    dyp8 = zhi ? dyh : dyp8;

  float s1 = 0.f, s2 = 0.f, s3 = 0.f;
  elem(clo,   vC0.x, vC0.y, dxa, sxa, dya, sya, dxb - dxm1, dyb - dym1, ja, t40.x, s1, s2, s3);
  elem(vC0.x, vC0.y, vC0.z, dxb, sxb, dyb, syb, dxc - dxa,  dyc - dya,  jb, t40.y, s1, s2, s3);
  elem(vC0.y, vC0.z, vC0.w, dxc, sxc, dyc, syc, dxd - dxb,  dyd - dyb,  jc, t40.z, s1, s2, s3);
  elem(vC0.z, vC0.w, vC1.x, dxd, sxd, dyd, syd, dxe - dxc,  dye - dyc,  jd, t40.w, s1, s2, s3);
  elem(vC0.w, vC1.x, vC1.y, dxe, sxe, dye, sye, dxf - dxd,  dyf - dyd,  je, t41.x, s1, s2, s3);
  elem(vC1.x, vC1.y, vC1.z, dxf, sxf, dyf, syf, dxg - dxe,  dyg - dye,  jf, t41.y, s1, s2, s3);
  elem(vC1.y, vC1.z, vC1.w, dxg, sxg, dyg, syg, dxh - dxf,  dyh - dyf,  jg, t41.z, s1, s2, s3);
  elem(vC1.z, vC1.w, chi,   dxh, sxh, dyh, syh, dxp8 - dxg, dyp8 - dyg, jh, t41.w, s1, s2, s3);

  wave_reduce3(s1, s2, s3);
  __shared__ float l1[4], l2[4], l3[4];
  const int lane = tid & 63, wv = tid >> 6;
  if (lane == 0) { l1[wv] = s1; l2[wv] = s2; l3[wv] = s3; }
  __syncthreads();
  if (tid == 0) {
    partials[blockIdx.x]            = l1[0] + l1[1] + l1[2] + l1[3];
    partials[NBLK + blockIdx.x]     = l2[0] + l2[1] + l2[2] + l2[3];
    partials[2 * NBLK + blockIdx.x] = l3[0] + l3[1] + l3[2] + l3[3];
  }
}

__global__ __launch_bounds__(1024) void ace_final(
    const float* __restrict__ partials, float* __restrict__ out) {
  const int tid = threadIdx.x;
  float s1 = 0.f, s2 = 0.f, s3 = 0.f;
  const float4* p1 = (const float4*)(partials);
  const float4* p2 = (const float4*)(partials + NBLK);
  const float4* p3 = (const float4*)(partials + 2 * NBLK);
  for (int i = tid; i < NBLK / 4; i += 1024) {
    const float4 a = p1[i];
    const float4 b = p2[i];
    const float4 c = p3[i];
    s1 += (a.x + a.y) + (a.z + a.w);
    s2 += (b.x + b.y) + (b.z + b.w);
    s3 += (c.x + c.y) + (c.z + c.w);
  }
  wave_reduce3(s1, s2, s3);
  __shared__ float l1[16], l2[16], l3[16];
  const int lane = tid & 63, wv = tid >> 6;
  if (lane == 0) { l1[wv] = s1; l2[wv] = s2; l3[wv] = s3; }
  __syncthreads();
  if (tid == 0) {
    float S1 = 0.f, S2 = 0.f, S3 = 0.f;
#pragma unroll
    for (int w = 0; w < 16; ++w) { S1 += l1[w]; S2 += l2[w]; S3 += l3[w]; }
    out[0] = MIU_ * fabsf(S1) + fabsf(S2) + S3 + ALPHA_ * (float)NTOT;
  }
}

extern "C" void kernel_launch(void* const* d_in, const int* in_sizes, int n_in,
                              void* d_out, int out_size, void* d_ws, size_t ws_size,
                              hipStream_t stream) {
  const float* pred  = (const float*)d_in[0];   // y_pred
  const float* truth = (const float*)d_in[1];   // y_true
  float* out      = (float*)d_out;
  float* partials = (float*)d_ws;               // 3*NBLK floats = 73.7 KB

  ace_main<<<NBLK, 256, 0, stream>>>(pred, truth, partials);
  ace_final<<<1, 1024, 0, stream>>>(partials, out);
}

// Round 12
// 119.873 us; speedup vs baseline: 1.0057x; 1.0057x over previous
//
#include <hip/hip_runtime.h>

// ACELoss3D FINAL (revert to round-10 best: 118.28us measured).
// 4x4x128 block tile (512 thr, 4 elem/thread), 7 float4 loads/thread:
//  - z-halo via +-1 lane shuffles (lane i-1 holds z0-4..z0-1; clamp lanes
//    select-overridden, never cross a 32-lane z-line).
//  - inward y-neighbor via __shfl_xor(.,32) half-wave exchange (lanes 0-31 /
//    32-63 hold adjacent y rows); only the outward y row is loaded.
//  - sched_barrier(0) pins all 7 loads in flight (single waitcnt drain).
//  - two-kernel distinct-address reduction (single-line atomics cost ~125us:
//    R2/R3 lesson).
// Settled experiments: XCD swizzle neutral (R6); 8 elem/thread negative
// (R7 -5us, R11 -2.3us); 4x4 tile +3.5us (R9); y-exchange +2us (R10);
// sched_barrier +1.5us (R8). Residual ace_main ~28us is a mixed
// VALU-issue / L1-return / HBM bound with no single dominating pipe.

static constexpr int   NTOT   = 6 * 128 * 128 * 128;   // 12,582,912
static constexpr int   NBLK   = 6144;                  // 32x32 xy-tiles * 6 bc
static constexpr float ALPHA_ = 0.001f;
static constexpr float MIU_   = 1.0f;
static constexpr float EPS_   = 1e-8f;

__device__ __forceinline__ void wave_reduce3(float& a, float& b, float& c) {
#pragma unroll
  for (int off = 32; off > 0; off >>= 1) {
    a += __shfl_down(a, off);
    b += __shfl_down(b, off);
    c += __shfl_down(c, off);
  }
}

// One output element. di/dj = un-halved first diffs; sx/sy = uxp+uxm, uyp+uym;
// dik/djk/dij = un-halved mixed double-diffs. 2*cik*cjk*cij = 0.25*dik*djk*dij.
__device__ __forceinline__ void elem(
    float uzm, float u0, float uzp,
    float di, float sx, float dj, float sy,
    float dik, float djk, float dij,
    float t, float& s1, float& s2, float& s3) {
  const float dk  = uzp - uzm;
  const float ci2 = 0.25f * di * di;
  const float cj2 = 0.25f * dj * dj;
  const float ck2 = 0.25f * dk * dk;
  const float u2  = u0 + u0;
  const float cii = sx - u2;
  const float cjj = sy - u2;
  const float ckk = (uzp + uzm) - u2;
  const float ss  = ci2 + cj2 + ck2;
  const float ss1 = 1.f + ss;
  const float L = (cii + cjj) + ckk;
  const float M = fmaf(ci2, cii, fmaf(cj2, cjj, ck2 * ckk));
  float curv = fmaf(ss1, L, -M);
  curv = fmaf(-0.25f * dij, dik * djk, curv);
  const float len = __builtin_amdgcn_sqrtf(EPS_ + ss);
  s3 = fmaf(curv * curv, len * __builtin_amdgcn_rcpf(ss1), s3);
  const float tm1 = t - 1.f;
  s1 = fmaf(u0, tm1 * tm1, s1);
  s2 = fmaf(1.f - u0, t * t, s2);
}

__global__ __launch_bounds__(512, 4) void ace_main(
    const float* __restrict__ pred, const float* __restrict__ truth,
    float* __restrict__ partials) {
  const int tid = threadIdx.x;
  // Block -> (bc, y-tile, x-tile); thread -> (x-sub, y-sub, z-group).
  const int rem = blockIdx.x & 1023;        // 32x32 xy tiles
  const int bc  = blockIdx.x >> 10;         // 0..5
  const int x   = ((rem & 31) << 2)  + (tid >> 7);
  const int y   = ((rem >> 5) << 2)  + ((tid >> 5) & 3);
  const int z0  = (tid & 31) << 2;                         // 0,4,...,124
  const size_t base = ((size_t)bc) << 21;
  const float* __restrict__ bp = pred + base;

  // Wave halves: lanes 0-31 = even y-sub, lanes 32-63 = odd y-sub (adjacent y).
  const bool upper = (tid & 32) != 0;
  const float sgn  = upper ? 1.f : -1.f;
  const int yOut = upper ? ((y < 127) ? y + 1 : 127) : ((y > 0) ? y - 1 : 0);
  const int rO  = yOut << 7;
  const int rC  = y << 7;
  const int pC  = x << 14;
  const int pXp = ((x < 127) ? x + 1 : 127) << 14;
  const int pXm = ((x > 0)   ? x - 1 : 0)   << 14;

  // 7 float4 loads — all pinned in flight before any consumer.
  const float4 vC  = *(const float4*)(bp + pC  + rC + z0);
  const float4 vXP = *(const float4*)(bp + pXp + rC + z0);
  const float4 vXM = *(const float4*)(bp + pXm + rC + z0);
  const float4 vOY = *(const float4*)(bp + pC  + rO + z0);   // outward y row
  const float4 vOP = *(const float4*)(bp + pXp + rO + z0);
  const float4 vOM = *(const float4*)(bp + pXm + rO + z0);
  const float4 t4  = *(const float4*)(truth + base + pC + rC + z0);
#if defined(__has_builtin)
#if __has_builtin(__builtin_amdgcn_sched_barrier)
  __builtin_amdgcn_sched_barrier(0);   // keep all 7 loads issued before math
#endif
#endif

  // Center-row x combines.
  const float dxa = vXP.x - vXM.x, dxb = vXP.y - vXM.y;
  const float dxc = vXP.z - vXM.z, dxd = vXP.w - vXM.w;
  const float sxa = vXP.x + vXM.x, sxb = vXP.y + vXM.y;
  const float sxc = vXP.z + vXM.z, sxd = vXP.w + vXM.w;
  // Outward-row x-diff.
  const float dOa = vOP.x - vOM.x, dOb = vOP.y - vOM.y;
  const float dOc = vOP.z - vOM.z, dOd = vOP.w - vOM.w;

  // Inward y-neighbor via half-wave exchange (partner row is never clamped).
  const float iCa = __shfl_xor(vC.x, 32), iCb = __shfl_xor(vC.y, 32);
  const float iCc = __shfl_xor(vC.z, 32), iCd = __shfl_xor(vC.w, 32);
  const float iDa = __shfl_xor(dxa, 32),  iDb = __shfl_xor(dxb, 32);
  const float iDc = __shfl_xor(dxc, 32),  iDd = __shfl_xor(dxd, 32);

  // y combines: sy order-free; dy/j get the half sign.
  const float sya = iCa + vOY.x, syb = iCb + vOY.y;
  const float syc = iCc + vOY.z, syd = iCd + vOY.w;
  const float dya = sgn * (vOY.x - iCa), dyb = sgn * (vOY.y - iCb);
  const float dyc = sgn * (vOY.z - iCc), dyd = sgn * (vOY.w - iCd);
  const float ja  = sgn * (dOa - iDa),   jb  = sgn * (dOb - iDb);
  const float jc  = sgn * (dOc - iDc),   jd  = sgn * (dOd - iDd);

  // z-halo from adjacent lanes (lane i-1 holds z0-4..z0-1). Clamp lanes
  // (tid&31)==0 / ==31 are select-overridden, so the +-1 shuffles never leak
  // across the 32-lane z-line boundary (where y changes).
  const bool zlo = (z0 == 0), zhi = (z0 == 124);
  float clo  = __shfl_up  (vC.w, 1);  clo  = zlo ? vC.x : clo;
  float chi  = __shfl_down(vC.x, 1);  chi  = zhi ? vC.w : chi;
  float dxm1 = __shfl_up  (dxd, 1);   dxm1 = zlo ? dxa : dxm1;
  float dxp4 = __shfl_down(dxa, 1);   dxp4 = zhi ? dxd : dxp4;
  float dym1 = __shfl_up  (dyd, 1);   dym1 = zlo ? dya : dym1;
  float dyp4 = __shfl_down(dya, 1);   dyp4 = zhi ? dyd : dyp4;

  float s1 = 0.f, s2 = 0.f, s3 = 0.f;
  elem(clo,  vC.x, vC.y, dxa, sxa, dya, sya, dxb - dxm1, dyb - dym1, ja, t4.x, s1, s2, s3);
  elem(vC.x, vC.y, vC.z, dxb, sxb, dyb, syb, dxc - dxa,  dyc - dya,  jb, t4.y, s1, s2, s3);
  elem(vC.y, vC.z, vC.w, dxc, sxc, dyc, syc, dxd - dxb,  dyd - dyb,  jc, t4.z, s1, s2, s3);
  elem(vC.z, vC.w, chi,  dxd, sxd, dyd, syd, dxp4 - dxc, dyp4 - dyc, jd, t4.w, s1, s2, s3);

  wave_reduce3(s1, s2, s3);
  __shared__ float l1[8], l2[8], l3[8];
  const int lane = tid & 63, wv = tid >> 6;
  if (lane == 0) { l1[wv] = s1; l2[wv] = s2; l3[wv] = s3; }
  __syncthreads();
  if (tid == 0) {
    float p1 = 0.f, p2 = 0.f, p3 = 0.f;
#pragma unroll
    for (int w = 0; w < 8; ++w) { p1 += l1[w]; p2 += l2[w]; p3 += l3[w]; }
    partials[blockIdx.x]            = p1;
    partials[NBLK + blockIdx.x]     = p2;
    partials[2 * NBLK + blockIdx.x] = p3;
  }
}

__global__ __launch_bounds__(1024) void ace_final(
    const float* __restrict__ partials, float* __restrict__ out) {
  const int tid = threadIdx.x;
  float s1 = 0.f, s2 = 0.f, s3 = 0.f;
  const float4* p1 = (const float4*)(partials);
  const float4* p2 = (const float4*)(partials + NBLK);
  const float4* p3 = (const float4*)(partials + 2 * NBLK);
  for (int i = tid; i < NBLK / 4; i += 1024) {
    const float4 a = p1[i];
    const float4 b = p2[i];
    const float4 c = p3[i];
    s1 += (a.x + a.y) + (a.z + a.w);
    s2 += (b.x + b.y) + (b.z + b.w);
    s3 += (c.x + c.y) + (c.z + c.w);
  }
  wave_reduce3(s1, s2, s3);
  __shared__ float l1[16], l2[16], l3[16];
  const int lane = tid & 63, wv = tid >> 6;
  if (lane == 0) { l1[wv] = s1; l2[wv] = s2; l3[wv] = s3; }
  __syncthreads();
  if (tid == 0) {
    float S1 = 0.f, S2 = 0.f, S3 = 0.f;
#pragma unroll
    for (int w = 0; w < 16; ++w) { S1 += l1[w]; S2 += l2[w]; S3 += l3[w]; }
    out[0] = MIU_ * fabsf(S1) + fabsf(S2) + S3 + ALPHA_ * (float)NTOT;
  }
}

extern "C" void kernel_launch(void* const* d_in, const int* in_sizes, int n_in,
                              void* d_out, int out_size, void* d_ws, size_t ws_size,
                              hipStream_t stream) {
  const float* pred  = (const float*)d_in[0];   // y_pred
  const float* truth = (const float*)d_in[1];   // y_true
  float* out      = (float*)d_out;
  float* partials = (float*)d_ws;               // 3*NBLK floats = 73.7 KB

  ace_main<<<NBLK, 512, 0, stream>>>(pred, truth, partials);
  ace_final<<<1, 1024, 0, stream>>>(partials, out);
}